// Round 2
// baseline (561.264 us; speedup 1.0000x reference)
//
#include <hip/hip_runtime.h>

// Complex MHA: T=1024, B=4, E=1024, H=16, HD=64.  SCALING = 0.125.
// Pipeline (all GEMMs are real f16 C = A * B^T, fp32 accum, MFMA 16x16x32):
//  1. pack:  A_x = [x_re|x_im] (4096x2048), Bw_re=[wr|-wi], Bw_im=[wi|wr] (3072x2048)
//  2. proj:  P_re = A_x Bw_re^T, P_im = A_x Bw_im^T   (4096x3072)
//  3. pack_qk: per bh: A_q=[qr|qi]*0.125 (1024x128), B_k=[kr+ki|kr-ki] (1024x128),
//              B_v=[vr^T;vi^T] (128x1024)
//  4. qk:    awr[bh] = A_q B_k^T (1024x1024) f16 + per-block min/max partials
//  5. minmax reduce -> mn, sc=1/(mx-mn);  colsum[bh][n] = sum_k B_v[bh][n][k]
//     pack Bo_re=[owr|-owi], Bo_im=[owi|owr] (1024x2048) into dead BK region
//  6. attn:  acc = awr B_v^T ; val = sc*acc - sc*mn*colsum ; scatter into
//            A_attn=[attn_re|attn_im] (4096x2048) over dead AQ region
//  7. out:   d_out[0:4M)=A_attn Bo_re^T + ob_re ; [4M:8M)=A_attn Bo_im^T + ob_im
//  8. aw_avg: mean over h of awr, affine-corrected -> d_out[8M:12M)

using half8 = __attribute__((__ext_vector_type__(8))) _Float16;
using f32x4 = __attribute__((__ext_vector_type__(4))) float;

// ---------------- workspace layout (bytes), total ~176.1 MiB ----------------
static constexpr size_t OFF_AWR    = 0;                         // 64*1024*1024*2 = 134217728
static constexpr size_t OFF_AQ     = 134217728;                 // 64*1024*128*2  = 16777216
static constexpr size_t OFF_BK     = 150994944;                 // 16777216
static constexpr size_t OFF_BV     = 167772160;                 // 16777216
static constexpr size_t OFF_COLSUM = 184549376;                 // 8192*4
static constexpr size_t OFF_PMIN   = 184582144;                 // 4096*4
static constexpr size_t OFF_PMAX   = 184598528;                 // 4096*4
static constexpr size_t OFF_SCAL   = 184614912;                 // 2 floats
// lifetime overlays:
static constexpr size_t OFF_AATTN  = OFF_AQ;                    // after AQ dead (16Mi)
static constexpr size_t OFF_BORE   = OFF_BK;                    // after BK dead (4Mi)
static constexpr size_t OFF_BOIM   = OFF_BK + 4194304;          // (4Mi)
// early-phase buffers overlay the (later-written) awr region [0, 92.3MB):
static constexpr size_t OFF_AX     = 0;                         // 4096*2048*2 = 16777216
static constexpr size_t OFF_BWRE   = 16777216;                  // 3072*2048*2 = 12582912
static constexpr size_t OFF_BWIM   = 29360128;
static constexpr size_t OFF_PRE    = 41943040;                  // 4096*3072*2 = 25165824
static constexpr size_t OFF_PIM    = 67108864;                  // ends 92274688 < 134217728

// ---------------- shared GEMM core: 128x128 tile, BK=32, 4 waves ----------------
// A: (128 rows of lda) row-major f16, K-contiguous.  B: (128 rows of ldb) = B^T layout.
// C[m][n] = sum_k A[m][k]*B[n][k].  Per-thread acc 4x4 tiles of 16x16.
// Staging: 128 rows x 32 halfs per array = 4096 halfs; 256 threads x 2 x 16B loads.
__device__ __forceinline__ void gemm_core(const _Float16* __restrict__ A,
                                          const _Float16* __restrict__ B,
                                          int K, int lda, int ldb,
                                          f32x4 acc[4][4]) {
    __shared__ _Float16 As[128 * 40];   // rows padded 32->40 halfs (<=2-way bank alias)
    __shared__ _Float16 Bs[128 * 40];
    const int tid  = threadIdx.x;
    const int lane = tid & 63;
    const int w    = tid >> 6;
    const int wr   = w >> 1, wc = w & 1;
    const int quad = lane >> 4, l16 = lane & 15;
    const int srow   = tid >> 2;          // 0..63
    const int schunk = (tid & 3) * 8;     // 0,8,16,24 (halfs)

    #pragma unroll
    for (int i = 0; i < 4; i++)
        #pragma unroll
        for (int j = 0; j < 4; j++) acc[i][j] = (f32x4){0.f, 0.f, 0.f, 0.f};

    const _Float16* aptr0 = A + (size_t)srow * lda + schunk;
    const _Float16* aptr1 = aptr0 + (size_t)64 * lda;
    const _Float16* bptr0 = B + (size_t)srow * ldb + schunk;
    const _Float16* bptr1 = bptr0 + (size_t)64 * ldb;
    _Float16* asdst0 = &As[srow * 40 + schunk];
    _Float16* asdst1 = asdst0 + 64 * 40;
    _Float16* bsdst0 = &Bs[srow * 40 + schunk];
    _Float16* bsdst1 = bsdst0 + 64 * 40;

    for (int kt = 0; kt < K; kt += 32) {
        f32x4 av0 = *(const f32x4*)(aptr0 + kt);
        f32x4 av1 = *(const f32x4*)(aptr1 + kt);
        f32x4 bv0 = *(const f32x4*)(bptr0 + kt);
        f32x4 bv1 = *(const f32x4*)(bptr1 + kt);
        *(f32x4*)asdst0 = av0;
        *(f32x4*)asdst1 = av1;
        *(f32x4*)bsdst0 = bv0;
        *(f32x4*)bsdst1 = bv1;
        __syncthreads();
        half8 af[4], bf[4];
        #pragma unroll
        for (int i = 0; i < 4; i++)
            af[i] = *(const half8*)(&As[(wr * 64 + i * 16 + l16) * 40 + quad * 8]);
        #pragma unroll
        for (int j = 0; j < 4; j++)
            bf[j] = *(const half8*)(&Bs[(wc * 64 + j * 16 + l16) * 40 + quad * 8]);
        #pragma unroll
        for (int i = 0; i < 4; i++)
            #pragma unroll
            for (int j = 0; j < 4; j++)
                acc[i][j] = __builtin_amdgcn_mfma_f32_16x16x32_f16(af[i], bf[j], acc[i][j], 0, 0, 0);
        __syncthreads();
    }
}

// C/D layout: row = quad*4 + reg, col = l16 (verified m89/m91).
#define EPILOGUE_COORDS()                               \
    const int lane = threadIdx.x & 63;                  \
    const int w    = threadIdx.x >> 6;                  \
    const int wr   = w >> 1, wc = w & 1;                \
    const int quad = lane >> 4, l16 = lane & 15;

// ---------------- kernels ----------------

__global__ __launch_bounds__(256) void k_pack2(_Float16* __restrict__ dst,
                                               const float* __restrict__ s1,
                                               const float* __restrict__ s2,
                                               float sgn2, int n) {
    int i = blockIdx.x * 256 + threadIdx.x;
    if (i >= n) return;
    int r = i >> 10, c = i & 1023;
    size_t o = ((size_t)r << 11) + (size_t)c;
    dst[o]        = (_Float16)s1[i];
    dst[o + 1024] = (_Float16)(sgn2 * s2[i]);
}

__global__ __launch_bounds__(256) void k_gemm_f16(const _Float16* __restrict__ A,
                                                  const _Float16* __restrict__ B,
                                                  _Float16* __restrict__ C,
                                                  int K, int lda, int ldb, int ldc) {
    const int m0 = blockIdx.y * 128, n0 = blockIdx.x * 128;
    f32x4 acc[4][4];
    gemm_core(A + (size_t)m0 * lda, B + (size_t)n0 * ldb, K, lda, ldb, acc);
    EPILOGUE_COORDS();
    #pragma unroll
    for (int i = 0; i < 4; i++)
        #pragma unroll
        for (int j = 0; j < 4; j++)
            #pragma unroll
            for (int r = 0; r < 4; r++) {
                int m = m0 + wr * 64 + i * 16 + quad * 4 + r;
                int n = n0 + wc * 64 + j * 16 + l16;
                C[(size_t)m * ldc + n] = (_Float16)acc[i][j][r];
            }
}

__global__ __launch_bounds__(256) void k_pack_qk(const _Float16* __restrict__ Pre,
                                                 const _Float16* __restrict__ Pim,
                                                 const float* __restrict__ b_re,
                                                 const float* __restrict__ b_im,
                                                 _Float16* __restrict__ Aq,
                                                 _Float16* __restrict__ Bk,
                                                 _Float16* __restrict__ Bv) {
    int i = blockIdx.x * 256 + threadIdx.x;      // over bh(64) x t(1024) x hd(64)
    int hd = i & 63, t = (i >> 6) & 1023, bh = i >> 16;
    int b = bh >> 4, h = bh & 15;
    size_t mrow = (size_t)(t * 4 + b) * 3072;
    int e = h * 64 + hd;
    float qr = (float)Pre[mrow + e]        + b_re[e];
    float qi = (float)Pim[mrow + e]        + b_im[e];
    float kr = (float)Pre[mrow + 1024 + e] + b_re[1024 + e];
    float ki = (float)Pim[mrow + 1024 + e] + b_im[1024 + e];
    float vr = (float)Pre[mrow + 2048 + e] + b_re[2048 + e];
    float vi = (float)Pim[mrow + 2048 + e] + b_im[2048 + e];
    size_t qbase = ((size_t)bh * 1024 + t) * 128;
    Aq[qbase + hd]      = (_Float16)(qr * 0.125f);
    Aq[qbase + 64 + hd] = (_Float16)(qi * 0.125f);
    Bk[qbase + hd]      = (_Float16)(kr + ki);
    Bk[qbase + 64 + hd] = (_Float16)(kr - ki);
    size_t vbase = (size_t)bh * 131072;          // 128*1024
    Bv[vbase + (size_t)hd * 1024 + t]        = (_Float16)vr;
    Bv[vbase + (size_t)(64 + hd) * 1024 + t] = (_Float16)vi;
}

__global__ __launch_bounds__(256) void k_gemm_qk(const _Float16* __restrict__ Aq,
                                                 const _Float16* __restrict__ Bk,
                                                 _Float16* __restrict__ awr,
                                                 float* __restrict__ pmin,
                                                 float* __restrict__ pmax) {
    const int bh = blockIdx.z;
    const int m0 = blockIdx.y * 128, n0 = blockIdx.x * 128;
    f32x4 acc[4][4];
    gemm_core(Aq + (size_t)bh * 131072 + (size_t)m0 * 128,
              Bk + (size_t)bh * 131072 + (size_t)n0 * 128, 128, 128, 128, acc);
    EPILOGUE_COORDS();
    _Float16* C = awr + ((size_t)bh << 20);
    float tmn = 3.0e38f, tmx = -3.0e38f;
    #pragma unroll
    for (int i = 0; i < 4; i++)
        #pragma unroll
        for (int j = 0; j < 4; j++)
            #pragma unroll
            for (int r = 0; r < 4; r++) {
                float v = acc[i][j][r];
                tmn = fminf(tmn, v); tmx = fmaxf(tmx, v);
                int m = m0 + wr * 64 + i * 16 + quad * 4 + r;
                int n = n0 + wc * 64 + j * 16 + l16;
                C[((size_t)m << 10) + n] = (_Float16)v;
            }
    __shared__ float smn[256], smx[256];
    int tid = threadIdx.x;
    smn[tid] = tmn; smx[tid] = tmx;
    __syncthreads();
    for (int s = 128; s > 0; s >>= 1) {
        if (tid < s) { smn[tid] = fminf(smn[tid], smn[tid + s]); smx[tid] = fmaxf(smx[tid], smx[tid + s]); }
        __syncthreads();
    }
    if (tid == 0) {
        int bid = (blockIdx.z * gridDim.y + blockIdx.y) * gridDim.x + blockIdx.x;
        pmin[bid] = smn[0]; pmax[bid] = smx[0];
    }
}

__global__ __launch_bounds__(256) void k_minmax(const float* __restrict__ pmin,
                                                const float* __restrict__ pmax,
                                                int n, float* __restrict__ scal) {
    __shared__ float smn[256], smx[256];
    int tid = threadIdx.x;
    float mn = 3.0e38f, mx = -3.0e38f;
    for (int i = tid; i < n; i += 256) { mn = fminf(mn, pmin[i]); mx = fmaxf(mx, pmax[i]); }
    smn[tid] = mn; smx[tid] = mx;
    __syncthreads();
    for (int s = 128; s > 0; s >>= 1) {
        if (tid < s) { smn[tid] = fminf(smn[tid], smn[tid + s]); smx[tid] = fmaxf(smx[tid], smx[tid + s]); }
        __syncthreads();
    }
    if (tid == 0) { scal[0] = smn[0]; scal[1] = 1.0f / (smx[0] - smn[0]); }
}

__global__ __launch_bounds__(256) void k_colsum(const _Float16* __restrict__ Bv,
                                                float* __restrict__ colsum) {
    int row  = blockIdx.x * 4 + (threadIdx.x >> 6);   // 0..8191 = bh*128+n
    int lane = threadIdx.x & 63;
    const _Float16* p = Bv + (size_t)row * 1024;
    float s = 0.f;
    for (int i = lane; i < 1024; i += 64) s += (float)p[i];
    #pragma unroll
    for (int off = 32; off > 0; off >>= 1) s += __shfl_down(s, off, 64);
    if (lane == 0) colsum[row] = s;
}

__global__ __launch_bounds__(256) void k_gemm_attn(const _Float16* __restrict__ awr,
                                                   const _Float16* __restrict__ Bv,
                                                   _Float16* __restrict__ Aattn,
                                                   const float* __restrict__ scal,
                                                   const float* __restrict__ colsum) {
    const int bh = blockIdx.z;
    const int m0 = blockIdx.y * 128;                 // N=128 -> single block col
    f32x4 acc[4][4];
    gemm_core(awr + ((size_t)bh << 20) + (size_t)m0 * 1024,
              Bv + (size_t)bh * 131072, 1024, 1024, 1024, acc);
    EPILOGUE_COORDS();
    const float sc = scal[1];
    const float c0 = sc * scal[0];                   // sc*mn
    const int b = bh >> 4, h = bh & 15;
    #pragma unroll
    for (int i = 0; i < 4; i++)
        #pragma unroll
        for (int j = 0; j < 4; j++)
            #pragma unroll
            for (int r = 0; r < 4; r++) {
                int m = m0 + wr * 64 + i * 16 + quad * 4 + r;   // q position
                int n = wc * 64 + j * 16 + l16;                 // 0..127
                float v = sc * acc[i][j][r] - c0 * colsum[bh * 128 + n];
                int e = (n < 64) ? (h * 64 + n) : (1024 + h * 64 + n - 64);
                Aattn[(size_t)(m * 4 + b) * 2048 + e] = (_Float16)v;
            }
}

__global__ __launch_bounds__(256) void k_gemm_out(const _Float16* __restrict__ A,
                                                  const _Float16* __restrict__ B,
                                                  float* __restrict__ outp,
                                                  const float* __restrict__ bias) {
    const int m0 = blockIdx.y * 128, n0 = blockIdx.x * 128;
    f32x4 acc[4][4];
    gemm_core(A + (size_t)m0 * 2048, B + (size_t)n0 * 2048, 2048, 2048, 2048, acc);
    EPILOGUE_COORDS();
    #pragma unroll
    for (int i = 0; i < 4; i++)
        #pragma unroll
        for (int j = 0; j < 4; j++)
            #pragma unroll
            for (int r = 0; r < 4; r++) {
                int m = m0 + wr * 64 + i * 16 + quad * 4 + r;
                int n = n0 + wc * 64 + j * 16 + l16;
                outp[((size_t)m << 10) + n] = acc[i][j][r] + bias[n];
            }
}

__global__ __launch_bounds__(256) void k_awavg(const _Float16* __restrict__ awr,
                                               const float* __restrict__ scal,
                                               float* __restrict__ out) {
    int i = blockIdx.x * 256 + threadIdx.x;          // over b(4) x q(1024) x k8(128)
    int k = (i & 127) * 8, q = (i >> 7) & 1023, b = i >> 17;
    float s[8] = {0, 0, 0, 0, 0, 0, 0, 0};
    size_t base = ((size_t)b << 24) + ((size_t)q << 10) + k;
    #pragma unroll
    for (int h = 0; h < 16; h++) {
        half8 v = *(const half8*)(awr + base + ((size_t)h << 20));
        #pragma unroll
        for (int e = 0; e < 8; e++) s[e] += (float)v[e];
    }
    const float mn = scal[0], sc = scal[1];
    float* dst = out + ((size_t)b << 20) + ((size_t)q << 10) + k;
    f32x4 o0, o1;
    #pragma unroll
    for (int e = 0; e < 4; e++) o0[e] = (s[e] * 0.0625f - mn) * sc;
    #pragma unroll
    for (int e = 0; e < 4; e++) o1[e] = (s[4 + e] * 0.0625f - mn) * sc;
    *(f32x4*)dst = o0;
    *(f32x4*)(dst + 4) = o1;
}

extern "C" void kernel_launch(void* const* d_in, const int* in_sizes, int n_in,
                              void* d_out, int out_size, void* d_ws, size_t ws_size,
                              hipStream_t stream) {
    const float* x_re  = (const float*)d_in[0];
    const float* x_im  = (const float*)d_in[1];
    const float* w_re  = (const float*)d_in[2];
    const float* w_im  = (const float*)d_in[3];
    const float* b_re  = (const float*)d_in[4];
    const float* b_im  = (const float*)d_in[5];
    const float* ow_re = (const float*)d_in[6];
    const float* ow_im = (const float*)d_in[7];
    const float* ob_re = (const float*)d_in[8];
    const float* ob_im = (const float*)d_in[9];

    char* ws = (char*)d_ws;
    _Float16* AWR   = (_Float16*)(ws + OFF_AWR);
    _Float16* AQ    = (_Float16*)(ws + OFF_AQ);
    _Float16* BK    = (_Float16*)(ws + OFF_BK);
    _Float16* BV    = (_Float16*)(ws + OFF_BV);
    _Float16* AATTN = (_Float16*)(ws + OFF_AATTN);
    _Float16* BORE  = (_Float16*)(ws + OFF_BORE);
    _Float16* BOIM  = (_Float16*)(ws + OFF_BOIM);
    float*    CSUM  = (float*)(ws + OFF_COLSUM);
    float*    PMIN  = (float*)(ws + OFF_PMIN);
    float*    PMAX  = (float*)(ws + OFF_PMAX);
    float*    SCAL  = (float*)(ws + OFF_SCAL);
    _Float16* AX    = (_Float16*)(ws + OFF_AX);
    _Float16* BWRE  = (_Float16*)(ws + OFF_BWRE);
    _Float16* BWIM  = (_Float16*)(ws + OFF_BWIM);
    _Float16* PRE   = (_Float16*)(ws + OFF_PRE);
    _Float16* PIM   = (_Float16*)(ws + OFF_PIM);

    // 1. input packing (in-proj operands)
    k_pack2<<<16384, 256, 0, stream>>>(AX,   x_re,  x_im,   1.f, 4096 * 1024);
    k_pack2<<<12288, 256, 0, stream>>>(BWRE, w_re,  w_im,  -1.f, 3072 * 1024);
    k_pack2<<<12288, 256, 0, stream>>>(BWIM, w_im,  w_re,   1.f, 3072 * 1024);
    // 2. in-projection (complex via two real K=2048 GEMMs)
    dim3 g1(24, 32);
    k_gemm_f16<<<g1, 256, 0, stream>>>(AX, BWRE, PRE, 2048, 2048, 2048, 3072);
    k_gemm_f16<<<g1, 256, 0, stream>>>(AX, BWIM, PIM, 2048, 2048, 2048, 3072);
    // 3. qkv repack (+bias, q scaling, k+-combine, v transpose)
    k_pack_qk<<<16384, 256, 0, stream>>>(PRE, PIM, b_re, b_im, AQ, BK, BV);
    // 4. QK^T (re+im fused into one real GEMM) + min/max partials
    dim3 g2(8, 8, 64);
    k_gemm_qk<<<g2, 256, 0, stream>>>(AQ, BK, AWR, PMIN, PMAX);
    // 5. scalar reduce + v column sums; pack out-proj operands into dead BK
    k_minmax<<<1, 256, 0, stream>>>(PMIN, PMAX, 4096, SCAL);
    k_colsum<<<2048, 256, 0, stream>>>(BV, CSUM);
    k_pack2<<< 4096, 256, 0, stream>>>(BORE, ow_re, ow_im, -1.f, 1024 * 1024);
    k_pack2<<< 4096, 256, 0, stream>>>(BOIM, ow_im, ow_re,  1.f, 1024 * 1024);
    // 6. attention x V with affine (min-max) correction in epilogue (AATTN over dead AQ)
    dim3 g3(1, 8, 64);
    k_gemm_attn<<<g3, 256, 0, stream>>>(AWR, BV, AATTN, SCAL, CSUM);
    // 7. out-projection -> d_out (re, im)
    dim3 g4(8, 32);
    k_gemm_out<<<g4, 256, 0, stream>>>(AATTN, BORE, (float*)d_out, ob_re);
    k_gemm_out<<<g4, 256, 0, stream>>>(AATTN, BOIM, (float*)d_out + 4194304, ob_im);
    // 8. head-averaged attention map
    k_awavg<<<2048, 256, 0, stream>>>(AWR, SCAL, (float*)d_out + 8388608);
}

// Round 3
// 508.368 us; speedup vs baseline: 1.1041x; 1.1041x over previous
//
#include <hip/hip_runtime.h>

// Complex MHA: T=1024, B=4, E=1024, H=16, HD=64.  SCALING = 0.125.
// Pipeline (all GEMMs are real f16 C = A * B^T, fp32 accum, MFMA 16x16x32):
//  1. pack:  A_x = [x_re|x_im] (4096x2048), Bw_re=[wr|-wi], Bw_im=[wi|wr] (3072x2048)
//  2. proj:  P_re = A_x Bw_re^T, P_im = A_x Bw_im^T   (4096x3072)
//  3. pack_qk: per bh: A_q=[qr|qi]*0.125 (1024x128), B_k=[kr+ki|kr-ki] (1024x128),
//              B_v=[vr^T;vi^T] (128x1024, transposed through LDS)
//  4. qk:    awr[bh] = A_q B_k^T (1024x1024) f16 + per-block min/max partials
//  5. minmax reduce -> mn, sc=1/(mx-mn);  colsum[bh][n] = sum_k B_v[bh][n][k]
//     pack Bo_re=[owr|-owi], Bo_im=[owi|owr] (1024x2048) into dead BK region
//  6. attn:  acc = awr B_v^T ; val = sc*acc - sc*mn*colsum ; scatter into
//            A_attn=[attn_re|attn_im] (4096x2048) over dead AQ region
//  7. out:   d_out[0:4M)=A_attn Bo_re^T + ob_re ; [4M:8M)=A_attn Bo_im^T + ob_im
//  8. aw_avg: mean over h of awr, affine-corrected -> d_out[8M:12M)
//
// GEMM core (this round): m97-style global_load_lds(16B) staging into unpadded
// 128x32 LDS tiles, XOR chunk swizzle to cut ds_read_b128 bank aliasing.

using half4 = __attribute__((__ext_vector_type__(4))) _Float16;
using half8 = __attribute__((__ext_vector_type__(8))) _Float16;
using f32x4 = __attribute__((__ext_vector_type__(4))) float;

// ---------------- workspace layout (bytes), total ~176.1 MiB ----------------
static constexpr size_t OFF_AWR    = 0;                         // 64*1024*1024*2 = 134217728
static constexpr size_t OFF_AQ     = 134217728;                 // 64*1024*128*2  = 16777216
static constexpr size_t OFF_BK     = 150994944;                 // 16777216
static constexpr size_t OFF_BV     = 167772160;                 // 16777216
static constexpr size_t OFF_COLSUM = 184549376;                 // 8192*4
static constexpr size_t OFF_PMIN   = 184582144;                 // 4096*4
static constexpr size_t OFF_PMAX   = 184598528;                 // 4096*4
static constexpr size_t OFF_SCAL   = 184614912;                 // 2 floats
// lifetime overlays:
static constexpr size_t OFF_AATTN  = OFF_AQ;                    // after AQ dead (16Mi)
static constexpr size_t OFF_BORE   = OFF_BK;                    // after BK dead (4Mi)
static constexpr size_t OFF_BOIM   = OFF_BK + 4194304;          // (4Mi)
// early-phase buffers overlay the (later-written) awr region [0, 92.3MB):
static constexpr size_t OFF_AX     = 0;                         // 4096*2048*2 = 16777216
static constexpr size_t OFF_BWRE   = 16777216;                  // 3072*2048*2 = 12582912
static constexpr size_t OFF_BWIM   = 29360128;
static constexpr size_t OFF_PRE    = 41943040;                  // 4096*3072*2 = 25165824
static constexpr size_t OFF_PIM    = 67108864;                  // ends 92274688 < 134217728

static __device__ __forceinline__ void gload_lds16(const void* g, void* l) {
    __builtin_amdgcn_global_load_lds(
        (__attribute__((address_space(1))) void*)(g),
        (__attribute__((address_space(3))) void*)(l), 16, 0, 0);
}

// ---------------- shared GEMM core: 128x128 tile, BK=32, 4 waves ----------------
// A: (128 rows of lda) row-major f16, K-contiguous.  B: (128 rows of ldb) = B^T layout.
// C[m][n] = sum_k A[m][k]*B[n][k].  Per-thread acc 4x4 tiles of 16x16.
// Staging: 4 global_load_lds(16B) per thread per iter (2 A-chunks + 2 B-chunks
// per wave); LDS slot s of row r holds global 8-half chunk s^(r&3).
__device__ __forceinline__ void gemm_core(const _Float16* __restrict__ A,
                                          const _Float16* __restrict__ B,
                                          int K, int lda, int ldb,
                                          f32x4 acc[4][4]) {
    __shared__ _Float16 As[128 * 32];
    __shared__ _Float16 Bs[128 * 32];
    const int tid  = threadIdx.x;
    const int lane = tid & 63;
    const int w    = tid >> 6;
    const int wr   = w >> 1, wc = w & 1;
    const int quad = lane >> 4, l16 = lane & 15;
    // staging coords: wave w owns chunks {2w, 2w+1} (16 rows x 32 halfs each)
    const int sr     = lane >> 2;               // 0..15 row within chunk
    const int gchunk = (lane & 3) ^ (sr & 3);   // xor-swizzled global 8-half chunk
    const int r0     = w * 32 + sr;
    const int r1     = r0 + 16;
    const _Float16* ap0 = A + (size_t)r0 * lda + gchunk * 8;
    const _Float16* ap1 = A + (size_t)r1 * lda + gchunk * 8;
    const _Float16* bp0 = B + (size_t)r0 * ldb + gchunk * 8;
    const _Float16* bp1 = B + (size_t)r1 * ldb + gchunk * 8;
    _Float16* lA0 = &As[(w * 2 + 0) * 512];
    _Float16* lA1 = &As[(w * 2 + 1) * 512];
    _Float16* lB0 = &Bs[(w * 2 + 0) * 512];
    _Float16* lB1 = &Bs[(w * 2 + 1) * 512];

    #pragma unroll
    for (int i = 0; i < 4; i++)
        #pragma unroll
        for (int j = 0; j < 4; j++) acc[i][j] = (f32x4){0.f, 0.f, 0.f, 0.f};

    const int rsw = l16 & 3;                    // frag row & 3 (for un-swizzle)
    for (int kt = 0; kt < K; kt += 32) {
        gload_lds16(ap0 + kt, lA0);
        gload_lds16(ap1 + kt, lA1);
        gload_lds16(bp0 + kt, lB0);
        gload_lds16(bp1 + kt, lB1);
        __syncthreads();
        half8 af[4], bf[4];
        #pragma unroll
        for (int i = 0; i < 4; i++)
            af[i] = *(const half8*)(&As[(wr * 64 + i * 16 + l16) * 32 + ((quad ^ rsw) * 8)]);
        #pragma unroll
        for (int j = 0; j < 4; j++)
            bf[j] = *(const half8*)(&Bs[(wc * 64 + j * 16 + l16) * 32 + ((quad ^ rsw) * 8)]);
        #pragma unroll
        for (int i = 0; i < 4; i++)
            #pragma unroll
            for (int j = 0; j < 4; j++)
                acc[i][j] = __builtin_amdgcn_mfma_f32_16x16x32_f16(af[i], bf[j], acc[i][j], 0, 0, 0);
        __syncthreads();
    }
}

// C/D layout: row = quad*4 + reg, col = l16 (verified m89/m91).
#define EPILOGUE_COORDS()                               \
    const int lane = threadIdx.x & 63;                  \
    const int w    = threadIdx.x >> 6;                  \
    const int wr   = w >> 1, wc = w & 1;                \
    const int quad = lane >> 4, l16 = lane & 15;

// ---------------- kernels ----------------

// vectorized pack: 4 elements/thread; dst row = [s1 | sgn2*s2]
__global__ __launch_bounds__(256) void k_pack2(_Float16* __restrict__ dst,
                                               const float* __restrict__ s1,
                                               const float* __restrict__ s2,
                                               float sgn2, int n4) {
    int i4 = blockIdx.x * 256 + threadIdx.x;
    if (i4 >= n4) return;
    int r = i4 >> 8, c4 = (i4 & 255) << 2;
    size_t src = ((size_t)r << 10) + c4;
    f32x4 a = *(const f32x4*)(s1 + src);
    f32x4 b = *(const f32x4*)(s2 + src);
    half4 ha, hb;
    #pragma unroll
    for (int e = 0; e < 4; e++) { ha[e] = (_Float16)a[e]; hb[e] = (_Float16)(sgn2 * b[e]); }
    size_t o = ((size_t)r << 11) + c4;
    *(half4*)(dst + o)        = ha;
    *(half4*)(dst + o + 1024) = hb;
}

__global__ __launch_bounds__(256) void k_gemm_f16(const _Float16* __restrict__ A,
                                                  const _Float16* __restrict__ B,
                                                  _Float16* __restrict__ C,
                                                  int K, int lda, int ldb, int ldc) {
    const int m0 = blockIdx.y * 128, n0 = blockIdx.x * 128;
    f32x4 acc[4][4];
    gemm_core(A + (size_t)m0 * lda, B + (size_t)n0 * ldb, K, lda, ldb, acc);
    EPILOGUE_COORDS();
    #pragma unroll
    for (int i = 0; i < 4; i++)
        #pragma unroll
        for (int j = 0; j < 4; j++)
            #pragma unroll
            for (int r = 0; r < 4; r++) {
                int m = m0 + wr * 64 + i * 16 + quad * 4 + r;
                int n = n0 + wc * 64 + j * 16 + l16;
                C[(size_t)m * ldc + n] = (_Float16)acc[i][j][r];
            }
}

// per (bh, 64-t slab): build Aq, Bk (coalesced) and Bv (transposed via LDS)
__global__ __launch_bounds__(256) void k_pack_qk(const _Float16* __restrict__ Pre,
                                                 const _Float16* __restrict__ Pim,
                                                 const float* __restrict__ b_re,
                                                 const float* __restrict__ b_im,
                                                 _Float16* __restrict__ Aq,
                                                 _Float16* __restrict__ Bk,
                                                 _Float16* __restrict__ Bv) {
    __shared__ _Float16 vt[128 * 66];            // [hd2][tloc], pad 64->66
    const int bh = blockIdx.y, t0 = blockIdx.x * 64;
    const int b = bh >> 4, h = bh & 15;
    const int tid = threadIdx.x;
    const int hd = tid & 63, tg = tid >> 6;      // 4 t-rows per pass
    const int e = h * 64 + hd;
    for (int pass = 0; pass < 16; pass++) {
        int tloc = pass * 4 + tg;
        int t = t0 + tloc;
        size_t mrow = (size_t)(t * 4 + b) * 3072;
        float qr = (float)Pre[mrow + e]        + b_re[e];
        float qi = (float)Pim[mrow + e]        + b_im[e];
        float kr = (float)Pre[mrow + 1024 + e] + b_re[1024 + e];
        float ki = (float)Pim[mrow + 1024 + e] + b_im[1024 + e];
        float vr = (float)Pre[mrow + 2048 + e] + b_re[2048 + e];
        float vi = (float)Pim[mrow + 2048 + e] + b_im[2048 + e];
        size_t qbase = ((size_t)bh * 1024 + t) * 128;
        Aq[qbase + hd]      = (_Float16)(qr * 0.125f);
        Aq[qbase + 64 + hd] = (_Float16)(qi * 0.125f);
        Bk[qbase + hd]      = (_Float16)(kr + ki);
        Bk[qbase + 64 + hd] = (_Float16)(kr - ki);
        vt[hd * 66 + tloc]        = (_Float16)vr;
        vt[(64 + hd) * 66 + tloc] = (_Float16)vi;
    }
    __syncthreads();
    // write Bv rows: 4 threads cover one row's 64 cols (2 x half8 each)
    size_t vbase = (size_t)bh * 131072;          // 128*1024
    const int j = tid & 3;
    #pragma unroll
    for (int half_ = 0; half_ < 2; half_++) {
        int r = (tid >> 2) + half_ * 64;
        _Float16* dst = Bv + vbase + (size_t)r * 1024 + t0 + j * 16;
        const _Float16* src = &vt[r * 66 + j * 16];
        *(half8*)dst       = *(const half8*)src;
        *(half8*)(dst + 8) = *(const half8*)(src + 8);
    }
}

__global__ __launch_bounds__(256) void k_gemm_qk(const _Float16* __restrict__ Aq,
                                                 const _Float16* __restrict__ Bk,
                                                 _Float16* __restrict__ awr,
                                                 float* __restrict__ pmin,
                                                 float* __restrict__ pmax) {
    const int bh = blockIdx.z;
    const int m0 = blockIdx.y * 128, n0 = blockIdx.x * 128;
    f32x4 acc[4][4];
    gemm_core(Aq + (size_t)bh * 131072 + (size_t)m0 * 128,
              Bk + (size_t)bh * 131072 + (size_t)n0 * 128, 128, 128, 128, acc);
    EPILOGUE_COORDS();
    _Float16* C = awr + ((size_t)bh << 20);
    float tmn = 3.0e38f, tmx = -3.0e38f;
    #pragma unroll
    for (int i = 0; i < 4; i++)
        #pragma unroll
        for (int j = 0; j < 4; j++)
            #pragma unroll
            for (int r = 0; r < 4; r++) {
                float v = acc[i][j][r];
                tmn = fminf(tmn, v); tmx = fmaxf(tmx, v);
                int m = m0 + wr * 64 + i * 16 + quad * 4 + r;
                int n = n0 + wc * 64 + j * 16 + l16;
                C[((size_t)m << 10) + n] = (_Float16)v;
            }
    __shared__ float smn[256], smx[256];
    int tid = threadIdx.x;
    smn[tid] = tmn; smx[tid] = tmx;
    __syncthreads();
    for (int s = 128; s > 0; s >>= 1) {
        if (tid < s) { smn[tid] = fminf(smn[tid], smn[tid + s]); smx[tid] = fmaxf(smx[tid], smx[tid + s]); }
        __syncthreads();
    }
    if (tid == 0) {
        int bid = (blockIdx.z * gridDim.y + blockIdx.y) * gridDim.x + blockIdx.x;
        pmin[bid] = smn[0]; pmax[bid] = smx[0];
    }
}

__global__ __launch_bounds__(256) void k_minmax(const float* __restrict__ pmin,
                                                const float* __restrict__ pmax,
                                                int n, float* __restrict__ scal) {
    __shared__ float smn[256], smx[256];
    int tid = threadIdx.x;
    float mn = 3.0e38f, mx = -3.0e38f;
    for (int i = tid; i < n; i += 256) { mn = fminf(mn, pmin[i]); mx = fmaxf(mx, pmax[i]); }
    smn[tid] = mn; smx[tid] = mx;
    __syncthreads();
    for (int s = 128; s > 0; s >>= 1) {
        if (tid < s) { smn[tid] = fminf(smn[tid], smn[tid + s]); smx[tid] = fmaxf(smx[tid], smx[tid + s]); }
        __syncthreads();
    }
    if (tid == 0) { scal[0] = smn[0]; scal[1] = 1.0f / (smx[0] - smn[0]); }
}

__global__ __launch_bounds__(256) void k_colsum(const _Float16* __restrict__ Bv,
                                                float* __restrict__ colsum) {
    int row  = blockIdx.x * 4 + (threadIdx.x >> 6);   // 0..8191 = bh*128+n
    int lane = threadIdx.x & 63;
    const _Float16* p = Bv + (size_t)row * 1024;
    float s = 0.f;
    for (int i = lane; i < 1024; i += 64) s += (float)p[i];
    #pragma unroll
    for (int off = 32; off > 0; off >>= 1) s += __shfl_down(s, off, 64);
    if (lane == 0) colsum[row] = s;
}

__global__ __launch_bounds__(256) void k_gemm_attn(const _Float16* __restrict__ awr,
                                                   const _Float16* __restrict__ Bv,
                                                   _Float16* __restrict__ Aattn,
                                                   const float* __restrict__ scal,
                                                   const float* __restrict__ colsum) {
    const int bh = blockIdx.z;
    const int m0 = blockIdx.y * 128;                 // N=128 -> single block col
    f32x4 acc[4][4];
    gemm_core(awr + ((size_t)bh << 20) + (size_t)m0 * 1024,
              Bv + (size_t)bh * 131072, 1024, 1024, 1024, acc);
    EPILOGUE_COORDS();
    const float sc = scal[1];
    const float c0 = sc * scal[0];                   // sc*mn
    const int b = bh >> 4, h = bh & 15;
    #pragma unroll
    for (int i = 0; i < 4; i++)
        #pragma unroll
        for (int j = 0; j < 4; j++)
            #pragma unroll
            for (int r = 0; r < 4; r++) {
                int m = m0 + wr * 64 + i * 16 + quad * 4 + r;   // q position
                int n = wc * 64 + j * 16 + l16;                 // 0..127
                float v = sc * acc[i][j][r] - c0 * colsum[bh * 128 + n];
                int e = (n < 64) ? (h * 64 + n) : (1024 + h * 64 + n - 64);
                Aattn[(size_t)(m * 4 + b) * 2048 + e] = (_Float16)v;
            }
}

__global__ __launch_bounds__(256) void k_gemm_out(const _Float16* __restrict__ A,
                                                  const _Float16* __restrict__ B,
                                                  float* __restrict__ outp,
                                                  const float* __restrict__ bias) {
    const int m0 = blockIdx.y * 128, n0 = blockIdx.x * 128;
    f32x4 acc[4][4];
    gemm_core(A + (size_t)m0 * 2048, B + (size_t)n0 * 2048, 2048, 2048, 2048, acc);
    EPILOGUE_COORDS();
    #pragma unroll
    for (int i = 0; i < 4; i++)
        #pragma unroll
        for (int j = 0; j < 4; j++)
            #pragma unroll
            for (int r = 0; r < 4; r++) {
                int m = m0 + wr * 64 + i * 16 + quad * 4 + r;
                int n = n0 + wc * 64 + j * 16 + l16;
                outp[((size_t)m << 10) + n] = acc[i][j][r] + bias[n];
            }
}

__global__ __launch_bounds__(256) void k_awavg(const _Float16* __restrict__ awr,
                                               const float* __restrict__ scal,
                                               float* __restrict__ out) {
    int i = blockIdx.x * 256 + threadIdx.x;          // over b(4) x q(1024) x k8(128)
    int k = (i & 127) * 8, q = (i >> 7) & 1023, b = i >> 17;
    float s[8] = {0, 0, 0, 0, 0, 0, 0, 0};
    size_t base = ((size_t)b << 24) + ((size_t)q << 10) + k;
    #pragma unroll
    for (int h = 0; h < 16; h++) {
        half8 v = *(const half8*)(awr + base + ((size_t)h << 20));
        #pragma unroll
        for (int e = 0; e < 8; e++) s[e] += (float)v[e];
    }
    const float mn = scal[0], sc = scal[1];
    float* dst = out + ((size_t)b << 20) + ((size_t)q << 10) + k;
    f32x4 o0, o1;
    #pragma unroll
    for (int e = 0; e < 4; e++) o0[e] = (s[e] * 0.0625f - mn) * sc;
    #pragma unroll
    for (int e = 0; e < 4; e++) o1[e] = (s[4 + e] * 0.0625f - mn) * sc;
    *(f32x4*)dst = o0;
    *(f32x4*)(dst + 4) = o1;
}

extern "C" void kernel_launch(void* const* d_in, const int* in_sizes, int n_in,
                              void* d_out, int out_size, void* d_ws, size_t ws_size,
                              hipStream_t stream) {
    const float* x_re  = (const float*)d_in[0];
    const float* x_im  = (const float*)d_in[1];
    const float* w_re  = (const float*)d_in[2];
    const float* w_im  = (const float*)d_in[3];
    const float* b_re  = (const float*)d_in[4];
    const float* b_im  = (const float*)d_in[5];
    const float* ow_re = (const float*)d_in[6];
    const float* ow_im = (const float*)d_in[7];
    const float* ob_re = (const float*)d_in[8];
    const float* ob_im = (const float*)d_in[9];

    char* ws = (char*)d_ws;
    _Float16* AWR   = (_Float16*)(ws + OFF_AWR);
    _Float16* AQ    = (_Float16*)(ws + OFF_AQ);
    _Float16* BK    = (_Float16*)(ws + OFF_BK);
    _Float16* BV    = (_Float16*)(ws + OFF_BV);
    _Float16* AATTN = (_Float16*)(ws + OFF_AATTN);
    _Float16* BORE  = (_Float16*)(ws + OFF_BORE);
    _Float16* BOIM  = (_Float16*)(ws + OFF_BOIM);
    float*    CSUM  = (float*)(ws + OFF_COLSUM);
    float*    PMIN  = (float*)(ws + OFF_PMIN);
    float*    PMAX  = (float*)(ws + OFF_PMAX);
    float*    SCAL  = (float*)(ws + OFF_SCAL);
    _Float16* AX    = (_Float16*)(ws + OFF_AX);
    _Float16* BWRE  = (_Float16*)(ws + OFF_BWRE);
    _Float16* BWIM  = (_Float16*)(ws + OFF_BWIM);
    _Float16* PRE   = (_Float16*)(ws + OFF_PRE);
    _Float16* PIM   = (_Float16*)(ws + OFF_PIM);

    // 1. input packing (in-proj operands), 4 elems/thread
    k_pack2<<<4096, 256, 0, stream>>>(AX,   x_re,  x_im,   1.f, 1048576);
    k_pack2<<<3072, 256, 0, stream>>>(BWRE, w_re,  w_im,  -1.f,  786432);
    k_pack2<<<3072, 256, 0, stream>>>(BWIM, w_im,  w_re,   1.f,  786432);
    // 2. in-projection (complex via two real K=2048 GEMMs)
    dim3 g1(24, 32);
    k_gemm_f16<<<g1, 256, 0, stream>>>(AX, BWRE, PRE, 2048, 2048, 2048, 3072);
    k_gemm_f16<<<g1, 256, 0, stream>>>(AX, BWIM, PIM, 2048, 2048, 2048, 3072);
    // 3. qkv repack (+bias, q scaling, k+-combine, v transpose via LDS)
    dim3 gp(16, 64);
    k_pack_qk<<<gp, 256, 0, stream>>>(PRE, PIM, b_re, b_im, AQ, BK, BV);
    // 4. QK^T (re+im fused into one real GEMM) + min/max partials
    dim3 g2(8, 8, 64);
    k_gemm_qk<<<g2, 256, 0, stream>>>(AQ, BK, AWR, PMIN, PMAX);
    // 5. scalar reduce + v column sums; pack out-proj operands into dead BK
    k_minmax<<<1, 256, 0, stream>>>(PMIN, PMAX, 4096, SCAL);
    k_colsum<<<2048, 256, 0, stream>>>(BV, CSUM);
    k_pack2<<<1024, 256, 0, stream>>>(BORE, ow_re, ow_im, -1.f, 262144);
    k_pack2<<<1024, 256, 0, stream>>>(BOIM, ow_im, ow_re,  1.f, 262144);
    // 6. attention x V with affine (min-max) correction in epilogue (AATTN over dead AQ)
    dim3 g3(1, 8, 64);
    k_gemm_attn<<<g3, 256, 0, stream>>>(AWR, BV, AATTN, SCAL, CSUM);
    // 7. out-projection -> d_out (re, im)
    dim3 g4(8, 32);
    k_gemm_out<<<g4, 256, 0, stream>>>(AATTN, BORE, (float*)d_out, ob_re);
    k_gemm_out<<<g4, 256, 0, stream>>>(AATTN, BOIM, (float*)d_out + 4194304, ob_im);
    // 8. head-averaged attention map
    k_awavg<<<2048, 256, 0, stream>>>(AWR, SCAL, (float*)d_out + 8388608);
}

// Round 5
// 467.974 us; speedup vs baseline: 1.1993x; 1.0863x over previous
//
#include <hip/hip_runtime.h>

// Complex MHA: T=1024, B=4, E=1024, H=16, HD=64.  SCALING = 0.125.
// Pipeline (all GEMMs real f16 C = A * B^T, fp32 accum, MFMA 16x16x32):
//  1. pack3:  AK0=xr, AK1=xi, AK2=xr+xi (4096x1024);  BW0=wr, BW1=wi, BW2=wr+wi (3072x1024)
//  2. proj (Karatsuba, one z=3 dispatch): T_z = AK_z BW_z^T  (4096x3072 each, K=1024)
//  3. pack_qk: P_re=T1-T2, P_im=T3-T1-T2 combined on the fly; per bh:
//              A_q=[qr|qi]*0.125 (1024x128), B_k=[kr+ki|kr-ki] (1024x128),
//              B_v=[vr^T;vi^T] (128x1024, transposed through LDS)
//  4. qk:    awr[bh] = A_q B_k^T (1024x1024) f16 + per-block min/max partials
//  5. minmax reduce -> mn, sc=1/(mx-mn);  colsum[bh][n] = sum_k B_v[bh][n][k]
//     pack Bo_re=[owr|-owi], Bo_im=[owi|owr] (1024x2048) into dead BK region
//  6. attn:  acc = awr B_v^T ; val = sc*acc - sc*mn*colsum -> A_attn (4096x2048)
//  7. out:   d_out = A_attn Bo_{re,im}^T + ob  (two K=2048 GEMMs, f32 out)
//  8. aw_avg: mean over h of awr, affine-corrected -> d_out[8M:12M)
//
// GEMM core: global_load_lds(16B) staging, unpadded 128x32 LDS tiles,
// XOR swizzle slot = chunk ^ ((row>>1)&3) -> exactly 2-way b128 aliasing (free).

using half4 = __attribute__((__ext_vector_type__(4))) _Float16;
using half8 = __attribute__((__ext_vector_type__(8))) _Float16;
using f32x4 = __attribute__((__ext_vector_type__(4))) float;

// ---------------- workspace layout (bytes), total ~176.1 MiB ----------------
static constexpr size_t OFF_AWR    = 0;                         // 64*1024*1024*2 = 134217728
static constexpr size_t OFF_AQ     = 134217728;                 // 64*1024*128*2  = 16777216
static constexpr size_t OFF_BK     = 150994944;                 // 16777216
static constexpr size_t OFF_BV     = 167772160;                 // 16777216
static constexpr size_t OFF_COLSUM = 184549376;                 // 8192*4
static constexpr size_t OFF_PMIN   = 184582144;                 // 4096*4
static constexpr size_t OFF_PMAX   = 184598528;                 // 4096*4
static constexpr size_t OFF_SCAL   = 184614912;                 // 2 floats
// lifetime overlays:
static constexpr size_t OFF_AATTN  = OFF_AQ;                    // after AQ dead (16Mi)
static constexpr size_t OFF_BORE   = OFF_BK;                    // after BK dead (4Mi)
static constexpr size_t OFF_BOIM   = OFF_BK + 4194304;          // (4Mi)
// phase-1 buffers overlay the (later-written) awr region [0, 119.5MB):
static constexpr size_t OFF_AK0    = 0;                         // 3 x 4096*1024*2
static constexpr size_t AK_STRIDE  = 8388608;
static constexpr size_t OFF_BW0    = 25165824;                  // 3 x 3072*1024*2
static constexpr size_t BW_STRIDE  = 6291456;
static constexpr size_t OFF_PT0    = 44040192;                  // 3 x 4096*3072*2
static constexpr size_t PT_STRIDE  = 25165824;                  // ends 119537664 < 134217728

static __device__ __forceinline__ void gload_lds16(const void* g, void* l) {
    __builtin_amdgcn_global_load_lds(
        (__attribute__((address_space(1))) void*)(g),
        (__attribute__((address_space(3))) void*)(l), 16, 0, 0);
}

// ---------------- shared GEMM core: 128x128 tile, BK=32, 4 waves ----------------
// A: 128 rows of lda, K-contiguous.  B: 128 rows of ldb (= B^T layout).
// C[m][n] = sum_k A[m][k]*B[n][k].  LDS row r slot s holds global chunk s^((r>>1)&3).
__device__ __forceinline__ void gemm_core(const _Float16* __restrict__ A,
                                          const _Float16* __restrict__ B,
                                          int K, int lda, int ldb,
                                          f32x4 acc[4][4]) {
    __shared__ _Float16 As[128 * 32];
    __shared__ _Float16 Bs[128 * 32];
    const int tid  = threadIdx.x;
    const int lane = tid & 63;
    const int w    = tid >> 6;
    const int wr   = w >> 1, wc = w & 1;
    const int quad = lane >> 4, l16 = lane & 15;
    // staging: wave w owns LDS chunks {2w,2w+1} (16 rows x 32 halfs each)
    const int sr     = lane >> 2;                    // row within 16-row chunk
    const int gchunk = (lane & 3) ^ ((sr >> 1) & 3); // xor-swizzled 8-half chunk
    const int r0     = w * 32 + sr;
    const int r1     = r0 + 16;
    const _Float16* ap0 = A + (size_t)r0 * lda + gchunk * 8;
    const _Float16* ap1 = A + (size_t)r1 * lda + gchunk * 8;
    const _Float16* bp0 = B + (size_t)r0 * ldb + gchunk * 8;
    const _Float16* bp1 = B + (size_t)r1 * ldb + gchunk * 8;
    _Float16* lA0 = &As[(w * 2 + 0) * 512];
    _Float16* lA1 = &As[(w * 2 + 1) * 512];
    _Float16* lB0 = &Bs[(w * 2 + 0) * 512];
    _Float16* lB1 = &Bs[(w * 2 + 1) * 512];

    #pragma unroll
    for (int i = 0; i < 4; i++)
        #pragma unroll
        for (int j = 0; j < 4; j++) acc[i][j] = (f32x4){0.f, 0.f, 0.f, 0.f};

    const int rsw = (l16 >> 1) & 3;                  // (row>>1)&3 for frag rows
    for (int kt = 0; kt < K; kt += 32) {
        gload_lds16(ap0 + kt, lA0);
        gload_lds16(ap1 + kt, lA1);
        gload_lds16(bp0 + kt, lB0);
        gload_lds16(bp1 + kt, lB1);
        __syncthreads();
        half8 af[4], bf[4];
        #pragma unroll
        for (int i = 0; i < 4; i++)
            af[i] = *(const half8*)(&As[(wr * 64 + i * 16 + l16) * 32 + ((quad ^ rsw) * 8)]);
        #pragma unroll
        for (int j = 0; j < 4; j++)
            bf[j] = *(const half8*)(&Bs[(wc * 64 + j * 16 + l16) * 32 + ((quad ^ rsw) * 8)]);
        #pragma unroll
        for (int i = 0; i < 4; i++)
            #pragma unroll
            for (int j = 0; j < 4; j++)
                acc[i][j] = __builtin_amdgcn_mfma_f32_16x16x32_f16(af[i], bf[j], acc[i][j], 0, 0, 0);
        __syncthreads();
    }
}

// C/D layout: row = quad*4 + reg, col = l16 (verified m89/m91).
#define EPILOGUE_COORDS()                               \
    const int lane = threadIdx.x & 63;                  \
    const int w    = threadIdx.x >> 6;                  \
    const int wr   = w >> 1, wc = w & 1;                \
    const int quad = lane >> 4, l16 = lane & 15;

// ---------------- kernels ----------------

// pack three Karatsuba operands: d0=s1, d1=s2, d2=s1+s2 (flat, 4 elems/thread)
__global__ __launch_bounds__(256) void k_pack3(_Float16* __restrict__ d0,
                                               _Float16* __restrict__ d1,
                                               _Float16* __restrict__ d2,
                                               const float* __restrict__ s1,
                                               const float* __restrict__ s2, int n4) {
    int i4 = blockIdx.x * 256 + threadIdx.x;
    if (i4 >= n4) return;
    size_t idx = (size_t)i4 << 2;
    f32x4 a = *(const f32x4*)(s1 + idx);
    f32x4 b = *(const f32x4*)(s2 + idx);
    half4 h0, h1, h2;
    #pragma unroll
    for (int e = 0; e < 4; e++) {
        h0[e] = (_Float16)a[e]; h1[e] = (_Float16)b[e]; h2[e] = (_Float16)(a[e] + b[e]);
    }
    *(half4*)(d0 + idx) = h0;
    *(half4*)(d1 + idx) = h1;
    *(half4*)(d2 + idx) = h2;
}

// vectorized pack: 4 elements/thread; dst row = [s1 | sgn2*s2]
__global__ __launch_bounds__(256) void k_pack2(_Float16* __restrict__ dst,
                                               const float* __restrict__ s1,
                                               const float* __restrict__ s2,
                                               float sgn2, int n4) {
    int i4 = blockIdx.x * 256 + threadIdx.x;
    if (i4 >= n4) return;
    int r = i4 >> 8, c4 = (i4 & 255) << 2;
    size_t src = ((size_t)r << 10) + c4;
    f32x4 a = *(const f32x4*)(s1 + src);
    f32x4 b = *(const f32x4*)(s2 + src);
    half4 ha, hb;
    #pragma unroll
    for (int e = 0; e < 4; e++) { ha[e] = (_Float16)a[e]; hb[e] = (_Float16)(sgn2 * b[e]); }
    size_t o = ((size_t)r << 11) + c4;
    *(half4*)(dst + o)        = ha;
    *(half4*)(dst + o + 1024) = hb;
}

// Karatsuba proj: z selects (AK_z, BW_z) -> T_z,  K=1024, C ld 3072
__global__ __launch_bounds__(256) void k_gemm_proj(const _Float16* __restrict__ AK,
                                                   const _Float16* __restrict__ BW,
                                                   _Float16* __restrict__ PT) {
    const int z = blockIdx.z;
    const _Float16* A = AK + (size_t)z * (AK_STRIDE / 2);
    const _Float16* B = BW + (size_t)z * (BW_STRIDE / 2);
    _Float16*       C = PT + (size_t)z * (PT_STRIDE / 2);
    const int m0 = blockIdx.y * 128, n0 = blockIdx.x * 128;
    f32x4 acc[4][4];
    gemm_core(A + (size_t)m0 * 1024, B + (size_t)n0 * 1024, 1024, 1024, 1024, acc);
    EPILOGUE_COORDS();
    #pragma unroll
    for (int i = 0; i < 4; i++)
        #pragma unroll
        for (int j = 0; j < 4; j++)
            #pragma unroll
            for (int r = 0; r < 4; r++) {
                int m = m0 + wr * 64 + i * 16 + quad * 4 + r;
                int n = n0 + wc * 64 + j * 16 + l16;
                C[(size_t)m * 3072 + n] = (_Float16)acc[i][j][r];
            }
}

// per (bh, 64-t slab): combine T1,T2,T3 -> q,k,v; build Aq, Bk (coalesced) and
// Bv (transposed via LDS)
__global__ __launch_bounds__(256) void k_pack_qk(const _Float16* __restrict__ T1,
                                                 const _Float16* __restrict__ T2,
                                                 const _Float16* __restrict__ T3,
                                                 const float* __restrict__ b_re,
                                                 const float* __restrict__ b_im,
                                                 _Float16* __restrict__ Aq,
                                                 _Float16* __restrict__ Bk,
                                                 _Float16* __restrict__ Bv) {
    __shared__ _Float16 vt[128 * 66];            // [hd2][tloc], pad 64->66
    const int bh = blockIdx.y, t0 = blockIdx.x * 64;
    const int b = bh >> 4, h = bh & 15;
    const int tid = threadIdx.x;
    const int hd = tid & 63, tg = tid >> 6;      // 4 t-rows per pass
    const int e = h * 64 + hd;
    for (int pass = 0; pass < 16; pass++) {
        int tloc = pass * 4 + tg;
        int t = t0 + tloc;
        size_t mrow = (size_t)(t * 4 + b) * 3072;
        float q1 = (float)T1[mrow + e], q2 = (float)T2[mrow + e], q3 = (float)T3[mrow + e];
        float k1 = (float)T1[mrow + 1024 + e], k2 = (float)T2[mrow + 1024 + e], k3 = (float)T3[mrow + 1024 + e];
        float v1 = (float)T1[mrow + 2048 + e], v2 = (float)T2[mrow + 2048 + e], v3 = (float)T3[mrow + 2048 + e];
        float qr = q1 - q2 + b_re[e];
        float qi = q3 - q1 - q2 + b_im[e];
        float kr = k1 - k2 + b_re[1024 + e];
        float ki = k3 - k1 - k2 + b_im[1024 + e];
        float vr = v1 - v2 + b_re[2048 + e];
        float vi = v3 - v1 - v2 + b_im[2048 + e];
        size_t qbase = ((size_t)bh * 1024 + t) * 128;
        Aq[qbase + hd]      = (_Float16)(qr * 0.125f);
        Aq[qbase + 64 + hd] = (_Float16)(qi * 0.125f);
        Bk[qbase + hd]      = (_Float16)(kr + ki);
        Bk[qbase + 64 + hd] = (_Float16)(kr - ki);
        vt[hd * 66 + tloc]        = (_Float16)vr;
        vt[(64 + hd) * 66 + tloc] = (_Float16)vi;
    }
    __syncthreads();
    // write Bv rows: 4 threads cover one row's 64 cols (2 x half8 each)
    size_t vbase = (size_t)bh * 131072;          // 128*1024
    const int j = tid & 3;
    #pragma unroll
    for (int half_ = 0; half_ < 2; half_++) {
        int r = (tid >> 2) + half_ * 64;
        _Float16* dst = Bv + vbase + (size_t)r * 1024 + t0 + j * 16;
        const _Float16* src = &vt[r * 66 + j * 16];
        *(half8*)dst       = *(const half8*)src;
        *(half8*)(dst + 8) = *(const half8*)(src + 8);
    }
}

__global__ __launch_bounds__(256) void k_gemm_qk(const _Float16* __restrict__ Aq,
                                                 const _Float16* __restrict__ Bk,
                                                 _Float16* __restrict__ awr,
                                                 float* __restrict__ pmin,
                                                 float* __restrict__ pmax) {
    const int bh = blockIdx.z;
    const int m0 = blockIdx.y * 128, n0 = blockIdx.x * 128;
    f32x4 acc[4][4];
    gemm_core(Aq + (size_t)bh * 131072 + (size_t)m0 * 128,
              Bk + (size_t)bh * 131072 + (size_t)n0 * 128, 128, 128, 128, acc);
    EPILOGUE_COORDS();
    _Float16* C = awr + ((size_t)bh << 20);
    float tmn = 3.0e38f, tmx = -3.0e38f;
    #pragma unroll
    for (int i = 0; i < 4; i++)
        #pragma unroll
        for (int j = 0; j < 4; j++)
            #pragma unroll
            for (int r = 0; r < 4; r++) {
                float v = acc[i][j][r];
                tmn = fminf(tmn, v); tmx = fmaxf(tmx, v);
                int m = m0 + wr * 64 + i * 16 + quad * 4 + r;
                int n = n0 + wc * 64 + j * 16 + l16;
                C[((size_t)m << 10) + n] = (_Float16)v;
            }
    __shared__ float smn[256], smx[256];
    int tid = threadIdx.x;
    smn[tid] = tmn; smx[tid] = tmx;
    __syncthreads();
    for (int s = 128; s > 0; s >>= 1) {
        if (tid < s) { smn[tid] = fminf(smn[tid], smn[tid + s]); smx[tid] = fmaxf(smx[tid], smx[tid + s]); }
        __syncthreads();
    }
    if (tid == 0) {
        int bid = (blockIdx.z * gridDim.y + blockIdx.y) * gridDim.x + blockIdx.x;
        pmin[bid] = smn[0]; pmax[bid] = smx[0];
    }
}

__global__ __launch_bounds__(256) void k_minmax(const float* __restrict__ pmin,
                                                const float* __restrict__ pmax,
                                                int n, float* __restrict__ scal) {
    __shared__ float smn[256], smx[256];
    int tid = threadIdx.x;
    float mn = 3.0e38f, mx = -3.0e38f;
    for (int i = tid; i < n; i += 256) { mn = fminf(mn, pmin[i]); mx = fmaxf(mx, pmax[i]); }
    smn[tid] = mn; smx[tid] = mx;
    __syncthreads();
    for (int s = 128; s > 0; s >>= 1) {
        if (tid < s) { smn[tid] = fminf(smn[tid], smn[tid + s]); smx[tid] = fmaxf(smx[tid], smx[tid + s]); }
        __syncthreads();
    }
    if (tid == 0) { scal[0] = smn[0]; scal[1] = 1.0f / (smx[0] - smn[0]); }
}

__global__ __launch_bounds__(256) void k_colsum(const _Float16* __restrict__ Bv,
                                                float* __restrict__ colsum) {
    int row  = blockIdx.x * 4 + (threadIdx.x >> 6);   // 0..8191 = bh*128+n
    int lane = threadIdx.x & 63;
    const _Float16* p = Bv + (size_t)row * 1024;
    float s = 0.f;
    for (int i = lane; i < 1024; i += 64) s += (float)p[i];
    #pragma unroll
    for (int off = 32; off > 0; off >>= 1) s += __shfl_down(s, off, 64);
    if (lane == 0) colsum[row] = s;
}

__global__ __launch_bounds__(256) void k_gemm_attn(const _Float16* __restrict__ awr,
                                                   const _Float16* __restrict__ Bv,
                                                   _Float16* __restrict__ Aattn,
                                                   const float* __restrict__ scal,
                                                   const float* __restrict__ colsum) {
    const int bh = blockIdx.z;
    const int m0 = blockIdx.y * 128;                 // N=128 -> single block col
    f32x4 acc[4][4];
    gemm_core(awr + ((size_t)bh << 20) + (size_t)m0 * 1024,
              Bv + (size_t)bh * 131072, 1024, 1024, 1024, acc);
    EPILOGUE_COORDS();
    const float sc = scal[1];
    const float c0 = sc * scal[0];                   // sc*mn
    const int b = bh >> 4, h = bh & 15;
    #pragma unroll
    for (int i = 0; i < 4; i++)
        #pragma unroll
        for (int j = 0; j < 4; j++)
            #pragma unroll
            for (int r = 0; r < 4; r++) {
                int m = m0 + wr * 64 + i * 16 + quad * 4 + r;   // q position
                int n = wc * 64 + j * 16 + l16;                 // 0..127
                float v = sc * acc[i][j][r] - c0 * colsum[bh * 128 + n];
                int e = (n < 64) ? (h * 64 + n) : (1024 + h * 64 + n - 64);
                Aattn[(size_t)(m * 4 + b) * 2048 + e] = (_Float16)v;
            }
}

__global__ __launch_bounds__(256) void k_gemm_out(const _Float16* __restrict__ A,
                                                  const _Float16* __restrict__ B,
                                                  float* __restrict__ outp,
                                                  const float* __restrict__ bias) {
    const int m0 = blockIdx.y * 128, n0 = blockIdx.x * 128;
    f32x4 acc[4][4];
    gemm_core(A + (size_t)m0 * 2048, B + (size_t)n0 * 2048, 2048, 2048, 2048, acc);
    EPILOGUE_COORDS();
    #pragma unroll
    for (int i = 0; i < 4; i++)
        #pragma unroll
        for (int j = 0; j < 4; j++)
            #pragma unroll
            for (int r = 0; r < 4; r++) {
                int m = m0 + wr * 64 + i * 16 + quad * 4 + r;
                int n = n0 + wc * 64 + j * 16 + l16;
                outp[((size_t)m << 10) + n] = acc[i][j][r] + bias[n];
            }
}

__global__ __launch_bounds__(256) void k_awavg(const _Float16* __restrict__ awr,
                                               const float* __restrict__ scal,
                                               float* __restrict__ out) {
    int i = blockIdx.x * 256 + threadIdx.x;          // over b(4) x q(1024) x k8(128)
    int k = (i & 127) * 8, q = (i >> 7) & 1023, b = i >> 17;
    float s[8] = {0, 0, 0, 0, 0, 0, 0, 0};
    size_t base = ((size_t)b << 24) + ((size_t)q << 10) + k;
    #pragma unroll
    for (int h = 0; h < 16; h++) {
        half8 v = *(const half8*)(awr + base + ((size_t)h << 20));
        #pragma unroll
        for (int e = 0; e < 8; e++) s[e] += (float)v[e];
    }
    const float mn = scal[0], sc = scal[1];
    float* dst = out + ((size_t)b << 20) + ((size_t)q << 10) + k;
    f32x4 o0, o1;
    #pragma unroll
    for (int e = 0; e < 4; e++) o0[e] = (s[e] * 0.0625f - mn) * sc;
    #pragma unroll
    for (int e = 0; e < 4; e++) o1[e] = (s[4 + e] * 0.0625f - mn) * sc;
    *(f32x4*)dst = o0;
    *(f32x4*)(dst + 4) = o1;
}

extern "C" void kernel_launch(void* const* d_in, const int* in_sizes, int n_in,
                              void* d_out, int out_size, void* d_ws, size_t ws_size,
                              hipStream_t stream) {
    const float* x_re  = (const float*)d_in[0];
    const float* x_im  = (const float*)d_in[1];
    const float* w_re  = (const float*)d_in[2];
    const float* w_im  = (const float*)d_in[3];
    const float* b_re  = (const float*)d_in[4];
    const float* b_im  = (const float*)d_in[5];
    const float* ow_re = (const float*)d_in[6];
    const float* ow_im = (const float*)d_in[7];
    const float* ob_re = (const float*)d_in[8];
    const float* ob_im = (const float*)d_in[9];

    char* ws = (char*)d_ws;
    _Float16* AWR   = (_Float16*)(ws + OFF_AWR);
    _Float16* AQ    = (_Float16*)(ws + OFF_AQ);
    _Float16* BK    = (_Float16*)(ws + OFF_BK);
    _Float16* BV    = (_Float16*)(ws + OFF_BV);
    _Float16* AATTN = (_Float16*)(ws + OFF_AATTN);
    _Float16* BORE  = (_Float16*)(ws + OFF_BORE);
    _Float16* BOIM  = (_Float16*)(ws + OFF_BOIM);
    float*    CSUM  = (float*)(ws + OFF_COLSUM);
    float*    PMIN  = (float*)(ws + OFF_PMIN);
    float*    PMAX  = (float*)(ws + OFF_PMAX);
    float*    SCAL  = (float*)(ws + OFF_SCAL);
    _Float16* AK    = (_Float16*)(ws + OFF_AK0);
    _Float16* BW    = (_Float16*)(ws + OFF_BW0);
    _Float16* PT    = (_Float16*)(ws + OFF_PT0);

    // 1. Karatsuba operand packing: AK0=xr, AK1=xi, AK2=xr+xi; BW likewise for w
    //    (4 elems/thread: blocks = n4/256)
    k_pack3<<<4096, 256, 0, stream>>>(AK, AK + AK_STRIDE / 2, AK + AK_STRIDE,
                                      x_re, x_im, 1048576);
    k_pack3<<<3072, 256, 0, stream>>>(BW, BW + BW_STRIDE / 2, BW + BW_STRIDE,
                                      w_re, w_im, 786432);
    // 2. in-projection: 3 Karatsuba GEMMs (K=1024) in one dispatch (2304 blocks)
    dim3 g1(24, 32, 3);
    k_gemm_proj<<<g1, 256, 0, stream>>>(AK, BW, PT);
    // 3. qkv repack: T1,T2,T3 -> complex proj (+bias, q scaling, k-combine, v transpose)
    dim3 gp(16, 64);
    k_pack_qk<<<gp, 256, 0, stream>>>(PT, PT + PT_STRIDE / 2, PT + PT_STRIDE,
                                      b_re, b_im, AQ, BK, BV);
    // 4. QK^T (re+im fused into one real GEMM) + min/max partials
    dim3 g2(8, 8, 64);
    k_gemm_qk<<<g2, 256, 0, stream>>>(AQ, BK, AWR, PMIN, PMAX);
    // 5. scalar reduce + v column sums; pack out-proj operands into dead BK
    k_minmax<<<1, 256, 0, stream>>>(PMIN, PMAX, 4096, SCAL);
    k_colsum<<<2048, 256, 0, stream>>>(BV, CSUM);
    k_pack2<<<1024, 256, 0, stream>>>(BORE, ow_re, ow_im, -1.f, 262144);
    k_pack2<<<1024, 256, 0, stream>>>(BOIM, ow_im, ow_re,  1.f, 262144);
    // 6. attention x V with affine (min-max) correction in epilogue (AATTN over dead AQ)
    dim3 g3(1, 8, 64);
    k_gemm_attn<<<g3, 256, 0, stream>>>(AWR, BV, AATTN, SCAL, CSUM);
    // 7. out-projection -> d_out (re, im), K=2048 direct (Karatsuba not worth it at N=1024)
    dim3 g4(8, 32);
    k_gemm_out<<<g4, 256, 0, stream>>>(AATTN, BORE, (float*)d_out, ob_re);
    k_gemm_out<<<g4, 256, 0, stream>>>(AATTN, BOIM, (float*)d_out + 4194304, ob_im);
    // 8. head-averaged attention map
    k_awavg<<<2048, 256, 0, stream>>>(AWR, SCAL, (float*)d_out + 8388608);
}

// Round 6
// 418.476 us; speedup vs baseline: 1.3412x; 1.1183x over previous
//
#include <hip/hip_runtime.h>

// Complex MHA: T=1024, B=4, E=1024, H=16, HD=64.  SCALING = 0.125.
// Pipeline (all GEMMs real f16 C = A * B^T, fp32 accum, MFMA 16x16x32):
//  1. pack3:  AK0=xr, AK1=xi, AK2=xr+xi (4096x1024);  BW0=wr, BW1=wi, BW2=wr+wi (3072x1024)
//  2. proj (Karatsuba, one z=3 dispatch): T_z = AK_z BW_z^T  (4096x3072 each, K=1024)
//  3. pack_qk: P_re=T1-T2, P_im=T3-T1-T2 combined on the fly; per bh:
//              A_q=[qr|qi]*0.125 (1024x128), B_k=[kr+ki|kr-ki] (1024x128),
//              B_v=[vr^T;vi^T] (128x1024, transposed through LDS)
//  4. qk:    awr[bh] = A_q B_k^T (1024x1024) f16 + per-block min/max partials
//  5. minmax reduce -> mn, sc=1/(mx-mn);  colsum[bh][n] = sum_k B_v[bh][n][k]
//     pack Bo_re=[owr|-owi], Bo_im=[owi|owr] (1024x2048) into dead BK region
//  6. attn:  acc = awr B_v^T ; val = sc*acc - sc*mn*colsum -> A_attn (4096x2048)
//  7. out (one z=2 dispatch): d_out = A_attn Bo_{re,im}^T + ob  (K=2048, f32 out)
//  8. aw_avg: mean over h of awr, affine-corrected -> d_out[8M:12M)
//
// GEMM core: BK=64 (half the barriers of BK=32), global_load_lds(16B) staging,
// unpadded 128x64 LDS tiles, XOR swizzle slot = chunk ^ (row&7) -> conflict-free.

using half4 = __attribute__((__ext_vector_type__(4))) _Float16;
using half8 = __attribute__((__ext_vector_type__(8))) _Float16;
using f32x4 = __attribute__((__ext_vector_type__(4))) float;

// ---------------- workspace layout (bytes), total ~176.1 MiB ----------------
static constexpr size_t OFF_AWR    = 0;                         // 64*1024*1024*2 = 134217728
static constexpr size_t OFF_AQ     = 134217728;                 // 64*1024*128*2  = 16777216
static constexpr size_t OFF_BK     = 150994944;                 // 16777216
static constexpr size_t OFF_BV     = 167772160;                 // 16777216
static constexpr size_t OFF_COLSUM = 184549376;                 // 8192*4
static constexpr size_t OFF_PMIN   = 184582144;                 // 4096*4
static constexpr size_t OFF_PMAX   = 184598528;                 // 4096*4
static constexpr size_t OFF_SCAL   = 184614912;                 // 2 floats
// lifetime overlays:
static constexpr size_t OFF_AATTN  = OFF_AQ;                    // after AQ dead (16Mi)
static constexpr size_t OFF_BORE   = OFF_BK;                    // after BK dead (4Mi)
static constexpr size_t OFF_BOIM   = OFF_BK + 4194304;          // (4Mi)
// phase-1 buffers overlay the (later-written) awr region [0, 119.5MB):
static constexpr size_t OFF_AK0    = 0;                         // 3 x 4096*1024*2
static constexpr size_t AK_STRIDE  = 8388608;
static constexpr size_t OFF_BW0    = 25165824;                  // 3 x 3072*1024*2
static constexpr size_t BW_STRIDE  = 6291456;
static constexpr size_t OFF_PT0    = 44040192;                  // 3 x 4096*3072*2
static constexpr size_t PT_STRIDE  = 25165824;                  // ends 119537664 < 134217728

static __device__ __forceinline__ void gload_lds16(const void* g, void* l) {
    __builtin_amdgcn_global_load_lds(
        (__attribute__((address_space(1))) void*)(g),
        (__attribute__((address_space(3))) void*)(l), 16, 0, 0);
}

// ---------------- shared GEMM core: 128x128 tile, BK=64, 4 waves ----------------
// A: 128 rows of lda, K-contiguous.  B: 128 rows of ldb (= B^T layout).
// C[m][n] = sum_k A[m][k]*B[n][k].
// LDS tile 128 rows x 64 halfs; row r slot s (8 halfs) holds global chunk s^(r&7).
// Staging: wave w covers rows [w*32,w*32+32), 4 x 1KB wave-loads per tile;
// lane layout within a wave-load: row = lane>>3, slot = lane&7 -> DMA lane*16B
// lands exactly row-major; global chunk = (lane&7)^(lane>>3) (row groups are
// 8-aligned so row&7 == lane>>3).
__device__ __forceinline__ void gemm_core(const _Float16* __restrict__ A,
                                          const _Float16* __restrict__ B,
                                          int K, int lda, int ldb,
                                          f32x4 acc[4][4]) {
    __shared__ _Float16 As[128 * 64];
    __shared__ _Float16 Bs[128 * 64];
    const int tid  = threadIdx.x;
    const int lane = tid & 63;
    const int w    = tid >> 6;
    const int wr   = w >> 1, wc = w & 1;
    const int quad = lane >> 4, l16 = lane & 15;
    const int grow = lane >> 3;                      // 0..7 row within 8-row group
    const int gcol = ((lane & 7) ^ grow) * 8;        // xor-swizzled 8-half chunk
    const _Float16* apw = A + (size_t)(w * 32 + grow) * lda + gcol;
    const _Float16* bpw = B + (size_t)(w * 32 + grow) * ldb + gcol;
    _Float16* lAw = &As[(w * 32) * 64];
    _Float16* lBw = &Bs[(w * 32) * 64];

    #pragma unroll
    for (int i = 0; i < 4; i++)
        #pragma unroll
        for (int j = 0; j < 4; j++) acc[i][j] = (f32x4){0.f, 0.f, 0.f, 0.f};

    const int rsw = l16 & 7;                         // frag row & 7 (un-swizzle)
    const int s0  = (quad ^ rsw) * 8;                // k-window [0,32)
    const int s1  = ((quad | 4) ^ rsw) * 8;          // k-window [32,64)
    for (int kt = 0; kt < K; kt += 64) {
        #pragma unroll
        for (int i = 0; i < 4; i++) {
            gload_lds16(apw + (size_t)(i * 8) * lda + kt, lAw + i * 512);
            gload_lds16(bpw + (size_t)(i * 8) * ldb + kt, lBw + i * 512);
        }
        __syncthreads();
        half8 af0[4], af1[4], bf0[4], bf1[4];
        #pragma unroll
        for (int i = 0; i < 4; i++) {
            const int row = (wr * 64 + i * 16 + l16) * 64;
            af0[i] = *(const half8*)(&As[row + s0]);
            af1[i] = *(const half8*)(&As[row + s1]);
        }
        #pragma unroll
        for (int j = 0; j < 4; j++) {
            const int row = (wc * 64 + j * 16 + l16) * 64;
            bf0[j] = *(const half8*)(&Bs[row + s0]);
            bf1[j] = *(const half8*)(&Bs[row + s1]);
        }
        #pragma unroll
        for (int i = 0; i < 4; i++)
            #pragma unroll
            for (int j = 0; j < 4; j++) {
                acc[i][j] = __builtin_amdgcn_mfma_f32_16x16x32_f16(af0[i], bf0[j], acc[i][j], 0, 0, 0);
                acc[i][j] = __builtin_amdgcn_mfma_f32_16x16x32_f16(af1[i], bf1[j], acc[i][j], 0, 0, 0);
            }
        __syncthreads();
    }
}

// C/D layout: row = quad*4 + reg, col = l16 (verified m89/m91).
#define EPILOGUE_COORDS()                               \
    const int lane = threadIdx.x & 63;                  \
    const int w    = threadIdx.x >> 6;                  \
    const int wr   = w >> 1, wc = w & 1;                \
    const int quad = lane >> 4, l16 = lane & 15;

// ---------------- kernels ----------------

// pack three Karatsuba operands: d0=s1, d1=s2, d2=s1+s2 (flat, 4 elems/thread)
__global__ __launch_bounds__(256) void k_pack3(_Float16* __restrict__ d0,
                                               _Float16* __restrict__ d1,
                                               _Float16* __restrict__ d2,
                                               const float* __restrict__ s1,
                                               const float* __restrict__ s2, int n4) {
    int i4 = blockIdx.x * 256 + threadIdx.x;
    if (i4 >= n4) return;
    size_t idx = (size_t)i4 << 2;
    f32x4 a = *(const f32x4*)(s1 + idx);
    f32x4 b = *(const f32x4*)(s2 + idx);
    half4 h0, h1, h2;
    #pragma unroll
    for (int e = 0; e < 4; e++) {
        h0[e] = (_Float16)a[e]; h1[e] = (_Float16)b[e]; h2[e] = (_Float16)(a[e] + b[e]);
    }
    *(half4*)(d0 + idx) = h0;
    *(half4*)(d1 + idx) = h1;
    *(half4*)(d2 + idx) = h2;
}

// vectorized pack: 4 elements/thread; dst row = [s1 | sgn2*s2]
__global__ __launch_bounds__(256) void k_pack2(_Float16* __restrict__ dst,
                                               const float* __restrict__ s1,
                                               const float* __restrict__ s2,
                                               float sgn2, int n4) {
    int i4 = blockIdx.x * 256 + threadIdx.x;
    if (i4 >= n4) return;
    int r = i4 >> 8, c4 = (i4 & 255) << 2;
    size_t src = ((size_t)r << 10) + c4;
    f32x4 a = *(const f32x4*)(s1 + src);
    f32x4 b = *(const f32x4*)(s2 + src);
    half4 ha, hb;
    #pragma unroll
    for (int e = 0; e < 4; e++) { ha[e] = (_Float16)a[e]; hb[e] = (_Float16)(sgn2 * b[e]); }
    size_t o = ((size_t)r << 11) + c4;
    *(half4*)(dst + o)        = ha;
    *(half4*)(dst + o + 1024) = hb;
}

// Karatsuba proj: z selects (AK_z, BW_z) -> T_z,  K=1024, C ld 3072
__global__ __launch_bounds__(256) void k_gemm_proj(const _Float16* __restrict__ AK,
                                                   const _Float16* __restrict__ BW,
                                                   _Float16* __restrict__ PT) {
    const int z = blockIdx.z;
    const _Float16* A = AK + (size_t)z * (AK_STRIDE / 2);
    const _Float16* B = BW + (size_t)z * (BW_STRIDE / 2);
    _Float16*       C = PT + (size_t)z * (PT_STRIDE / 2);
    const int m0 = blockIdx.y * 128, n0 = blockIdx.x * 128;
    f32x4 acc[4][4];
    gemm_core(A + (size_t)m0 * 1024, B + (size_t)n0 * 1024, 1024, 1024, 1024, acc);
    EPILOGUE_COORDS();
    #pragma unroll
    for (int i = 0; i < 4; i++)
        #pragma unroll
        for (int j = 0; j < 4; j++)
            #pragma unroll
            for (int r = 0; r < 4; r++) {
                int m = m0 + wr * 64 + i * 16 + quad * 4 + r;
                int n = n0 + wc * 64 + j * 16 + l16;
                C[(size_t)m * 3072 + n] = (_Float16)acc[i][j][r];
            }
}

// per (bh, 64-t slab): combine T1,T2,T3 -> q,k,v; build Aq, Bk (coalesced) and
// Bv (transposed via LDS)
__global__ __launch_bounds__(256) void k_pack_qk(const _Float16* __restrict__ T1,
                                                 const _Float16* __restrict__ T2,
                                                 const _Float16* __restrict__ T3,
                                                 const float* __restrict__ b_re,
                                                 const float* __restrict__ b_im,
                                                 _Float16* __restrict__ Aq,
                                                 _Float16* __restrict__ Bk,
                                                 _Float16* __restrict__ Bv) {
    __shared__ _Float16 vt[128 * 66];            // [hd2][tloc], pad 64->66
    const int bh = blockIdx.y, t0 = blockIdx.x * 64;
    const int b = bh >> 4, h = bh & 15;
    const int tid = threadIdx.x;
    const int hd = tid & 63, tg = tid >> 6;      // 4 t-rows per pass
    const int e = h * 64 + hd;
    for (int pass = 0; pass < 16; pass++) {
        int tloc = pass * 4 + tg;
        int t = t0 + tloc;
        size_t mrow = (size_t)(t * 4 + b) * 3072;
        float q1 = (float)T1[mrow + e], q2 = (float)T2[mrow + e], q3 = (float)T3[mrow + e];
        float k1 = (float)T1[mrow + 1024 + e], k2 = (float)T2[mrow + 1024 + e], k3 = (float)T3[mrow + 1024 + e];
        float v1 = (float)T1[mrow + 2048 + e], v2 = (float)T2[mrow + 2048 + e], v3 = (float)T3[mrow + 2048 + e];
        float qr = q1 - q2 + b_re[e];
        float qi = q3 - q1 - q2 + b_im[e];
        float kr = k1 - k2 + b_re[1024 + e];
        float ki = k3 - k1 - k2 + b_im[1024 + e];
        float vr = v1 - v2 + b_re[2048 + e];
        float vi = v3 - v1 - v2 + b_im[2048 + e];
        size_t qbase = ((size_t)bh * 1024 + t) * 128;
        Aq[qbase + hd]      = (_Float16)(qr * 0.125f);
        Aq[qbase + 64 + hd] = (_Float16)(qi * 0.125f);
        Bk[qbase + hd]      = (_Float16)(kr + ki);
        Bk[qbase + 64 + hd] = (_Float16)(kr - ki);
        vt[hd * 66 + tloc]        = (_Float16)vr;
        vt[(64 + hd) * 66 + tloc] = (_Float16)vi;
    }
    __syncthreads();
    // write Bv rows: 4 threads cover one row's 64 cols (2 x half8 each)
    size_t vbase = (size_t)bh * 131072;          // 128*1024
    const int j = tid & 3;
    #pragma unroll
    for (int half_ = 0; half_ < 2; half_++) {
        int r = (tid >> 2) + half_ * 64;
        _Float16* dst = Bv + vbase + (size_t)r * 1024 + t0 + j * 16;
        const _Float16* src = &vt[r * 66 + j * 16];
        *(half8*)dst       = *(const half8*)src;
        *(half8*)(dst + 8) = *(const half8*)(src + 8);
    }
}

__global__ __launch_bounds__(256) void k_gemm_qk(const _Float16* __restrict__ Aq,
                                                 const _Float16* __restrict__ Bk,
                                                 _Float16* __restrict__ awr,
                                                 float* __restrict__ pmin,
                                                 float* __restrict__ pmax) {
    const int bh = blockIdx.z;
    const int m0 = blockIdx.y * 128, n0 = blockIdx.x * 128;
    f32x4 acc[4][4];
    gemm_core(Aq + (size_t)bh * 131072 + (size_t)m0 * 128,
              Bk + (size_t)bh * 131072 + (size_t)n0 * 128, 128, 128, 128, acc);
    EPILOGUE_COORDS();
    _Float16* C = awr + ((size_t)bh << 20);
    float tmn = 3.0e38f, tmx = -3.0e38f;
    #pragma unroll
    for (int i = 0; i < 4; i++)
        #pragma unroll
        for (int j = 0; j < 4; j++)
            #pragma unroll
            for (int r = 0; r < 4; r++) {
                float v = acc[i][j][r];
                tmn = fminf(tmn, v); tmx = fmaxf(tmx, v);
                int m = m0 + wr * 64 + i * 16 + quad * 4 + r;
                int n = n0 + wc * 64 + j * 16 + l16;
                C[((size_t)m << 10) + n] = (_Float16)v;
            }
    __shared__ float smn[256], smx[256];
    int tid = threadIdx.x;
    smn[tid] = tmn; smx[tid] = tmx;
    __syncthreads();
    for (int s = 128; s > 0; s >>= 1) {
        if (tid < s) { smn[tid] = fminf(smn[tid], smn[tid + s]); smx[tid] = fmaxf(smx[tid], smx[tid + s]); }
        __syncthreads();
    }
    if (tid == 0) {
        int bid = (blockIdx.z * gridDim.y + blockIdx.y) * gridDim.x + blockIdx.x;
        pmin[bid] = smn[0]; pmax[bid] = smx[0];
    }
}

__global__ __launch_bounds__(256) void k_minmax(const float* __restrict__ pmin,
                                                const float* __restrict__ pmax,
                                                int n, float* __restrict__ scal) {
    __shared__ float smn[256], smx[256];
    int tid = threadIdx.x;
    float mn = 3.0e38f, mx = -3.0e38f;
    for (int i = tid; i < n; i += 256) { mn = fminf(mn, pmin[i]); mx = fmaxf(mx, pmax[i]); }
    smn[tid] = mn; smx[tid] = mx;
    __syncthreads();
    for (int s = 128; s > 0; s >>= 1) {
        if (tid < s) { smn[tid] = fminf(smn[tid], smn[tid + s]); smx[tid] = fmaxf(smx[tid], smx[tid + s]); }
        __syncthreads();
    }
    if (tid == 0) { scal[0] = smn[0]; scal[1] = 1.0f / (smx[0] - smn[0]); }
}

__global__ __launch_bounds__(256) void k_colsum(const _Float16* __restrict__ Bv,
                                                float* __restrict__ colsum) {
    int row  = blockIdx.x * 4 + (threadIdx.x >> 6);   // 0..8191 = bh*128+n
    int lane = threadIdx.x & 63;
    const _Float16* p = Bv + (size_t)row * 1024;
    float s = 0.f;
    for (int i = lane; i < 1024; i += 64) s += (float)p[i];
    #pragma unroll
    for (int off = 32; off > 0; off >>= 1) s += __shfl_down(s, off, 64);
    if (lane == 0) colsum[row] = s;
}

__global__ __launch_bounds__(256) void k_gemm_attn(const _Float16* __restrict__ awr,
                                                   const _Float16* __restrict__ Bv,
                                                   _Float16* __restrict__ Aattn,
                                                   const float* __restrict__ scal,
                                                   const float* __restrict__ colsum) {
    const int bh = blockIdx.z;
    const int m0 = blockIdx.y * 128;                 // N=128 -> single block col
    f32x4 acc[4][4];
    gemm_core(awr + ((size_t)bh << 20) + (size_t)m0 * 1024,
              Bv + (size_t)bh * 131072, 1024, 1024, 1024, acc);
    EPILOGUE_COORDS();
    const float sc = scal[1];
    const float c0 = sc * scal[0];                   // sc*mn
    const int b = bh >> 4, h = bh & 15;
    #pragma unroll
    for (int i = 0; i < 4; i++)
        #pragma unroll
        for (int j = 0; j < 4; j++)
            #pragma unroll
            for (int r = 0; r < 4; r++) {
                int m = m0 + wr * 64 + i * 16 + quad * 4 + r;   // q position
                int n = wc * 64 + j * 16 + l16;                 // 0..127
                float v = sc * acc[i][j][r] - c0 * colsum[bh * 128 + n];
                int e = (n < 64) ? (h * 64 + n) : (1024 + h * 64 + n - 64);
                Aattn[(size_t)(m * 4 + b) * 2048 + e] = (_Float16)v;
            }
}

// merged out-projection: z=0 -> re (Bre, ob_re), z=1 -> im (Bim, ob_im)
__global__ __launch_bounds__(256) void k_gemm_out2(const _Float16* __restrict__ A,
                                                   const _Float16* __restrict__ Bre,
                                                   const _Float16* __restrict__ Bim,
                                                   float* __restrict__ outp,
                                                   const float* __restrict__ ob_re,
                                                   const float* __restrict__ ob_im) {
    const int z = blockIdx.z;
    const _Float16* B = z ? Bim : Bre;
    const float* bias = z ? ob_im : ob_re;
    float* out = outp + (size_t)z * 4194304;
    const int m0 = blockIdx.y * 128, n0 = blockIdx.x * 128;
    f32x4 acc[4][4];
    gemm_core(A + (size_t)m0 * 2048, B + (size_t)n0 * 2048, 2048, 2048, 2048, acc);
    EPILOGUE_COORDS();
    #pragma unroll
    for (int i = 0; i < 4; i++)
        #pragma unroll
        for (int j = 0; j < 4; j++)
            #pragma unroll
            for (int r = 0; r < 4; r++) {
                int m = m0 + wr * 64 + i * 16 + quad * 4 + r;
                int n = n0 + wc * 64 + j * 16 + l16;
                out[((size_t)m << 10) + n] = acc[i][j][r] + bias[n];
            }
}

__global__ __launch_bounds__(256) void k_awavg(const _Float16* __restrict__ awr,
                                               const float* __restrict__ scal,
                                               float* __restrict__ out) {
    int i = blockIdx.x * 256 + threadIdx.x;          // over b(4) x q(1024) x k8(128)
    int k = (i & 127) * 8, q = (i >> 7) & 1023, b = i >> 17;
    float s[8] = {0, 0, 0, 0, 0, 0, 0, 0};
    size_t base = ((size_t)b << 24) + ((size_t)q << 10) + k;
    #pragma unroll
    for (int h = 0; h < 16; h++) {
        half8 v = *(const half8*)(awr + base + ((size_t)h << 20));
        #pragma unroll
        for (int e = 0; e < 8; e++) s[e] += (float)v[e];
    }
    const float mn = scal[0], sc = scal[1];
    float* dst = out + ((size_t)b << 20) + ((size_t)q << 10) + k;
    f32x4 o0, o1;
    #pragma unroll
    for (int e = 0; e < 4; e++) o0[e] = (s[e] * 0.0625f - mn) * sc;
    #pragma unroll
    for (int e = 0; e < 4; e++) o1[e] = (s[4 + e] * 0.0625f - mn) * sc;
    *(f32x4*)dst = o0;
    *(f32x4*)(dst + 4) = o1;
}

extern "C" void kernel_launch(void* const* d_in, const int* in_sizes, int n_in,
                              void* d_out, int out_size, void* d_ws, size_t ws_size,
                              hipStream_t stream) {
    const float* x_re  = (const float*)d_in[0];
    const float* x_im  = (const float*)d_in[1];
    const float* w_re  = (const float*)d_in[2];
    const float* w_im  = (const float*)d_in[3];
    const float* b_re  = (const float*)d_in[4];
    const float* b_im  = (const float*)d_in[5];
    const float* ow_re = (const float*)d_in[6];
    const float* ow_im = (const float*)d_in[7];
    const float* ob_re = (const float*)d_in[8];
    const float* ob_im = (const float*)d_in[9];

    char* ws = (char*)d_ws;
    _Float16* AWR   = (_Float16*)(ws + OFF_AWR);
    _Float16* AQ    = (_Float16*)(ws + OFF_AQ);
    _Float16* BK    = (_Float16*)(ws + OFF_BK);
    _Float16* BV    = (_Float16*)(ws + OFF_BV);
    _Float16* AATTN = (_Float16*)(ws + OFF_AATTN);
    _Float16* BORE  = (_Float16*)(ws + OFF_BORE);
    _Float16* BOIM  = (_Float16*)(ws + OFF_BOIM);
    float*    CSUM  = (float*)(ws + OFF_COLSUM);
    float*    PMIN  = (float*)(ws + OFF_PMIN);
    float*    PMAX  = (float*)(ws + OFF_PMAX);
    float*    SCAL  = (float*)(ws + OFF_SCAL);
    _Float16* AK    = (_Float16*)(ws + OFF_AK0);
    _Float16* BW    = (_Float16*)(ws + OFF_BW0);
    _Float16* PT    = (_Float16*)(ws + OFF_PT0);

    // 1. Karatsuba operand packing: AK0=xr, AK1=xi, AK2=xr+xi; BW likewise for w
    k_pack3<<<4096, 256, 0, stream>>>(AK, AK + AK_STRIDE / 2, AK + AK_STRIDE,
                                      x_re, x_im, 1048576);
    k_pack3<<<3072, 256, 0, stream>>>(BW, BW + BW_STRIDE / 2, BW + BW_STRIDE,
                                      w_re, w_im, 786432);
    // 2. in-projection: 3 Karatsuba GEMMs (K=1024) in one dispatch (2304 blocks)
    dim3 g1(24, 32, 3);
    k_gemm_proj<<<g1, 256, 0, stream>>>(AK, BW, PT);
    // 3. qkv repack: T1,T2,T3 -> complex proj (+bias, q scaling, k-combine, v transpose)
    dim3 gp(16, 64);
    k_pack_qk<<<gp, 256, 0, stream>>>(PT, PT + PT_STRIDE / 2, PT + PT_STRIDE,
                                      b_re, b_im, AQ, BK, BV);
    // 4. QK^T (re+im fused into one real GEMM) + min/max partials
    dim3 g2(8, 8, 64);
    k_gemm_qk<<<g2, 256, 0, stream>>>(AQ, BK, AWR, PMIN, PMAX);
    // 5. scalar reduce + v column sums; pack out-proj operands into dead BK
    k_minmax<<<1, 256, 0, stream>>>(PMIN, PMAX, 4096, SCAL);
    k_colsum<<<2048, 256, 0, stream>>>(BV, CSUM);
    k_pack2<<<1024, 256, 0, stream>>>(BORE, ow_re, ow_im, -1.f, 262144);
    k_pack2<<<1024, 256, 0, stream>>>(BOIM, ow_im, ow_re,  1.f, 262144);
    // 6. attention x V with affine (min-max) correction in epilogue (AATTN over dead AQ)
    dim3 g3(1, 8, 64);
    k_gemm_attn<<<g3, 256, 0, stream>>>(AWR, BV, AATTN, SCAL, CSUM);
    // 7. out-projection -> d_out (re, im) as one z=2 dispatch (512 blocks)
    dim3 g4(8, 32, 2);
    k_gemm_out2<<<g4, 256, 0, stream>>>(AATTN, BORE, BOIM, (float*)d_out, ob_re, ob_im);
    // 8. head-averaged attention map
    k_awavg<<<2048, 256, 0, stream>>>(AWR, SCAL, (float*)d_out + 8388608);
}